// Round 10
// baseline (3145.526 us; speedup 1.0000x reference)
//
#include <hip/hip_runtime.h>
#include <hip/hip_bf16.h>
#include <math.h>

#define E_DIM 1024
#define FF_DIM 4096
#define LAYERS 24
#define MPAD 384      // 24 * 16 token-row padding (rows 257..383 zero / ignored)
#define SPAD 288      // vT / P column padding (9 * 32)
#define KCP 608       // conv K (588) padded to 19*32

typedef __attribute__((ext_vector_type(8))) short short8;
typedef __attribute__((ext_vector_type(8))) __bf16 bf16x8;
typedef __attribute__((ext_vector_type(4))) float float4_t;
typedef __attribute__((ext_vector_type(4))) unsigned short ushort4_t;

union ABu { short8 s; bf16x8 b; };
union BFU { __bf16 b; unsigned short u; };

__device__ __forceinline__ float4_t MFMA(bf16x8 a, bf16x8 b, float4_t c) {
  return __builtin_amdgcn_mfma_f32_16x16x32_bf16(a, b, c, 0, 0, 0);
}
__device__ __forceinline__ float4_t MFMAs(short8 a, short8 b, float4_t c) {
  ABu ua, ub; ua.s = a; ub.s = b;
  return __builtin_amdgcn_mfma_f32_16x16x32_bf16(ua.b, ub.b, c, 0, 0, 0);
}
__device__ __forceinline__ unsigned short f2bf(float f) {
  BFU x; x.b = (__bf16)f; return x.u;
}

// async global->LDS: 16B per lane, LDS dest = wave-uniform base + lane*16
__device__ __forceinline__ void glds16(const float* src, float* dst) {
  __builtin_amdgcn_global_load_lds(
      (const __attribute__((address_space(1))) unsigned int*)src,
      (__attribute__((address_space(3))) unsigned int*)dst, 16, 0, 0);
}

// ---------------------------------------------------------------------------
// prep: im2col frame -> Pm ; conv_w -> Wp ; zero pads of h / ob / vT
// ---------------------------------------------------------------------------
__global__ void prep_kernel(const float* __restrict__ frame, const float* __restrict__ conv_w,
                            unsigned short* __restrict__ Pm, unsigned short* __restrict__ Wp,
                            unsigned short* __restrict__ h, unsigned short* __restrict__ ob,
                            unsigned short* __restrict__ vTb) {
  int b = blockIdx.x, tid = threadIdx.x;
  if (b < 256) {
    int pr = b >> 4, pc = b & 15;
    for (int kk = tid; kk < KCP; kk += 256) {
      unsigned short us = 0;
      if (kk < 588) {
        int c = kk / 196, rem = kk % 196;
        int i = rem / 14, j = rem % 14;
        us = f2bf(frame[c * 224 * 224 + (pr * 14 + i) * 224 + (pc * 14 + j)]);
      }
      Pm[b * KCP + kk] = us;
    }
  } else if (b < 1280) {
    int n = b - 256;
    for (int kk = tid; kk < KCP; kk += 256) {
      unsigned short us = (kk < 588) ? f2bf(conv_w[n * 588 + kk]) : (unsigned short)0;
      Wp[n * KCP + kk] = us;
    }
  } else {
    int idx = (b - 1280) * 256 + tid;
    const int NH = (MPAD - 257) * E_DIM;   // 130048
    const int NO = (MPAD - 272) * E_DIM;   // 114688
    const int NV = 16 * 64 * (SPAD - 272); // 16384
    if (idx < NH) {
      h[257 * E_DIM + idx] = 0;
    } else if (idx < NH + NO) {
      ob[272 * E_DIM + (idx - NH)] = 0;
    } else if (idx < NH + NO + NV) {
      int i = idx - NH - NO;
      vTb[(size_t)(i >> 4) * SPAD + 272 + (i & 15)] = 0;
    }
  }
}

// ---------------------------------------------------------------------------
// pb_cls
// ---------------------------------------------------------------------------
__global__ void pb_cls_kernel(const float* __restrict__ bboxes, const float* __restrict__ cls_emb,
                              float* __restrict__ pb, float* __restrict__ Mi, float* __restrict__ x) {
  __shared__ float sb[128];
  __shared__ float red[256];
  int tid = threadIdx.x;
  if (tid < 128) sb[tid] = bboxes[tid];
  __syncthreads();
  int p = tid;
  float px1 = (float)((p & 15) * 14), py1 = (float)((p >> 4) * 14);
  float px2 = px1 + 14.f, py2 = py1 + 14.f;
  float s = 0.f;
  for (int r = 0; r < 32; ++r) {
    float bx1 = sb[r * 4 + 0], by1 = sb[r * 4 + 1], bx2 = sb[r * 4 + 2], by2 = sb[r * 4 + 3];
    float iw = fmaxf(fminf(bx2, px2) - fmaxf(bx1, px1), 0.f);
    float ih = fmaxf(fminf(by2, py2) - fmaxf(by1, py1), 0.f);
    float ov = iw * ih * (1.f / 196.f);
    Mi[r * 256 + p] = ov;
    s += ov;
  }
  red[tid] = s;
  __syncthreads();
  for (int off = 128; off > 0; off >>= 1) {
    if (tid < off) red[tid] = fmaxf(red[tid], red[tid + off]);
    __syncthreads();
  }
  pb[p] = s / (red[0] + 1e-6f);
  for (int j = 0; j < 4; ++j) x[tid * 4 + j] = cls_emb[tid * 4 + j];
}

// ---------------------------------------------------------------------------
// conv GEMM
// ---------------------------------------------------------------------------
__global__ __launch_bounds__(256) void conv_gemm(const unsigned short* __restrict__ Pm,
                                                 const unsigned short* __restrict__ Wp,
                                                 float* __restrict__ x) {
  int n0 = blockIdx.x * 16;
  int tid = threadIdx.x, wave = tid >> 6, lane = tid & 63;
  int lg = lane >> 4, lc = lane & 15;
  float4_t acc[4] = {{0,0,0,0},{0,0,0,0},{0,0,0,0},{0,0,0,0}};
  const unsigned short* bp = Wp + (size_t)(n0 + lc) * KCP + lg * 8;
  const unsigned short* apt[4];
#pragma unroll
  for (int t = 0; t < 4; ++t) apt[t] = Pm + (size_t)((wave + t * 4) * 16 + lc) * KCP + lg * 8;
  for (int s = 0; s < 19; ++s) {
    short8 bf = *(const short8*)bp; bp += 32;
#pragma unroll
    for (int t = 0; t < 4; ++t) {
      short8 af = *(const short8*)apt[t]; apt[t] += 32;
      acc[t] = MFMAs(af, bf, acc[t]);
    }
  }
#pragma unroll
  for (int t = 0; t < 4; ++t) {
    int mbase = (wave + t * 4) * 16 + lg * 4;
#pragma unroll
    for (int r = 0; r < 4; ++r)
      x[(size_t)(1 + mbase + r) * E_DIM + n0 + lc] = fmaxf(acc[t][r], 0.f);
  }
}

// ---------------------------------------------------------------------------
// GEMM: C[m][n] = A[m][:] (bf16) . W[:][n] (fp32->bf16)
// Block = 512 threads (8 waves, 2/SIMD) x 32 N-cols x ALL 384 M-rows
//         (wave w owns m-tiles w*3..w*3+2) x K-chunk (NK x 128).
// Counted-vmcnt pipeline (never drain to 0 mid-loop): 3 LDS W-buffers, glds
// prefetch depth 2, A double-buffered in regs (issued oldest each iter).
// Per iter t: [issue A(t+1): 12 loads/wave] [issue glds(t+2): 2 ops/wave]
//             [compute t] [s_waitcnt vmcnt(2); s_barrier]
//   -> retires A(t+1)+glds(t+1), leaves glds(t+2) in flight.
// LDS col-XOR swizzle key=8*((row>>3)&3) applied on the glds SOURCE address.
// EPI 0: q/k/vT scatter (+bias)  EPI 1: quickgelu (+bias)  EPI 2: fp32 partial
// ---------------------------------------------------------------------------
template <int NTOT, int EPI, int NK>
__global__ __launch_bounds__(512, 1) void gemm_nk(
    const unsigned short* __restrict__ A, int lda,
    const float* __restrict__ Wa, const float* __restrict__ Wb2, const float* __restrict__ Wc,
    const float* __restrict__ ba, const float* __restrict__ bb, const float* __restrict__ bc,
    int NNT,
    unsigned short* __restrict__ oq, unsigned short* __restrict__ okk,
    unsigned short* __restrict__ ovT, unsigned short* __restrict__ om,
    float* __restrict__ opart) {
  static_assert(NK >= 2, "pipeline needs >=2 K-tiles");
  __shared__ __align__(16) float Wt[3][128][32];
  int b = blockIdx.x;
  int nt = b % NNT, ks = b / NNT;

  int tid = threadIdx.x, wave = tid >> 6, lane = tid & 63;
  int lg = lane >> 4, lc = lane & 15;

  const float* W; const float* bias; int ncl;
  if (EPI == 0) {
    int sel = nt >> 5; ncl = (nt & 31) << 5;
    W = (sel == 0) ? Wa : ((sel == 1) ? Wb2 : Wc);
    bias = (sel == 0) ? ba : ((sel == 1) ? bb : bc);
  } else {
    ncl = nt << 5; W = Wa; bias = ba;
  }

  const int kb0 = ks * (NK * 128);

  // staging: 2 glds/wave/tile; op g=wave*2+o covers rows [g*8, g*8+8)
  const float* wsrc[2];
  int dsto[2];
#pragma unroll
  for (int op = 0; op < 2; ++op) {
    int g = wave * 2 + op;              // 0..15
    int rbase = g * 8;
    int row = rbase + (lane >> 3);
    int key = 8 * (g & 3);              // row-group swizzle key
    int col = ((lane & 7) * 4) ^ key;
    wsrc[op] = W + (size_t)(kb0 + row) * NTOT + ncl + col;
    dsto[op] = __builtin_amdgcn_readfirstlane(rbase * 32);
  }

  const unsigned short* ap[3];
#pragma unroll
  for (int j = 0; j < 3; ++j) {
    int t0 = wave * 3 + j;
    ap[j] = A + (size_t)(t0 * 16 + lc) * lda + kb0 + lg * 8;
  }

  float4_t acc[6];   // [mtile j][frag f] -> acc[j*2+f]
#pragma unroll
  for (int i = 0; i < 6; ++i) acc[i] = (float4_t){0, 0, 0, 0};

  short8 av[2][12];
  // A(0) — issued first (oldest vmcnt entries)
#pragma unroll
  for (int s = 0; s < 4; ++s)
#pragma unroll
    for (int j = 0; j < 3; ++j)
      av[0][s * 3 + j] = *(const short8*)(ap[j] + s * 32);
#pragma unroll
  for (int j = 0; j < 3; ++j) ap[j] += 128;

  // glds tiles 0, 1
#pragma unroll
  for (int op = 0; op < 2; ++op) glds16(wsrc[op], &Wt[0][0][0] + dsto[op]);
#pragma unroll
  for (int op = 0; op < 2; ++op)
    glds16(wsrc[op] + (size_t)128 * NTOT, &Wt[1][0][0] + dsto[op]);
  // retire A(0)+glds(0); keep glds(1) in flight
  asm volatile("s_waitcnt vmcnt(2)\n\ts_barrier" ::: "memory");

  // read bases: addr = s*1024 + lg*256 + ((f*16+lc) ^ (8*lg)) + d*32
  const int cx0 = lg * 256 + (lc ^ (8 * lg));
  const int cx1 = lg * 256 + ((16 + lc) ^ (8 * lg));

#pragma unroll
  for (int t = 0; t < NK; ++t) {
    if (t + 1 < NK) {
#pragma unroll
      for (int s = 0; s < 4; ++s)
#pragma unroll
        for (int j = 0; j < 3; ++j)
          av[(t + 1) & 1][s * 3 + j] = *(const short8*)(ap[j] + s * 32);
#pragma unroll
      for (int j = 0; j < 3; ++j) ap[j] += 128;
    }
    if (t + 2 < NK) {
      float* bufn = &Wt[(t + 2) % 3][0][0];
#pragma unroll
      for (int op = 0; op < 2; ++op)
        glds16(wsrc[op] + (size_t)(t + 2) * 128 * NTOT, bufn + dsto[op]);
    }
    const float* Wb_ = &Wt[t % 3][0][0];
#pragma unroll
    for (int s = 0; s < 4; ++s) {
      bf16x8 wf0, wf1;
#pragma unroll
      for (int d = 0; d < 8; ++d) {
        wf0[d] = (__bf16)Wb_[s * 1024 + cx0 + d * 32];
        wf1[d] = (__bf16)Wb_[s * 1024 + cx1 + d * 32];
      }
#pragma unroll
      for (int j = 0; j < 3; ++j) {
        ABu a; a.s = av[t & 1][s * 3 + j];
        acc[j * 2 + 0] = MFMA(wf0, a.b, acc[j * 2 + 0]);
        acc[j * 2 + 1] = MFMA(wf1, a.b, acc[j * 2 + 1]);
      }
    }
    if (t + 1 < NK) {
      if (t + 2 < NK) asm volatile("s_waitcnt vmcnt(2)\n\ts_barrier" ::: "memory");
      else            asm volatile("s_waitcnt vmcnt(0)\n\ts_barrier" ::: "memory");
    }
  }

  float4_t bv0 = {0,0,0,0}, bv1 = {0,0,0,0};
  if (bias) {
    bv0 = *(const float4_t*)(bias + ncl + lg * 4);
    bv1 = *(const float4_t*)(bias + ncl + 16 + lg * 4);
  }

  if (EPI == 0) {
    int sel = nt >> 5;
    int head = ncl >> 6;
    int db0 = (ncl & 63) + lg * 4;
    int db1 = (ncl & 63) + 16 + lg * 4;
#pragma unroll
    for (int j = 0; j < 3; ++j) {
      int tile = wave * 3 + j;
      int m = tile * 16 + lc;
      if (sel < 2) {
        unsigned short* dst = (sel == 0 ? oq : okk) + ((size_t)(head * MPAD + m)) * 64;
        ushort4_t h0, h1;
#pragma unroll
        for (int r = 0; r < 4; ++r) {
          h0[r] = f2bf(acc[j * 2 + 0][r] + bv0[r]);
          h1[r] = f2bf(acc[j * 2 + 1][r] + bv1[r]);
        }
        *(ushort4_t*)(dst + db0) = h0;
        *(ushort4_t*)(dst + db1) = h1;
      } else if (tile < 17) {   // vT columns only exist for m < 272
#pragma unroll
        for (int r = 0; r < 4; ++r) {
          ovT[(size_t)(head * 64 + db0 + r) * SPAD + m] = f2bf(acc[j * 2 + 0][r] + bv0[r]);
          ovT[(size_t)(head * 64 + db1 + r) * SPAD + m] = f2bf(acc[j * 2 + 1][r] + bv1[r]);
        }
      }
    }
  } else if (EPI == 1) {
#pragma unroll
    for (int j = 0; j < 3; ++j) {
      int m = (wave * 3 + j) * 16 + lc;
      ushort4_t h0, h1;
#pragma unroll
      for (int r = 0; r < 4; ++r) {
        float v0 = acc[j * 2 + 0][r] + bv0[r];
        float v1 = acc[j * 2 + 1][r] + bv1[r];
        h0[r] = f2bf(v0 / (1.f + __expf(-1.702f * v0)));
        h1[r] = f2bf(v1 / (1.f + __expf(-1.702f * v1)));
      }
      *(ushort4_t*)(om + (size_t)m * FF_DIM + ncl + lg * 4) = h0;
      *(ushort4_t*)(om + (size_t)m * FF_DIM + ncl + 16 + lg * 4) = h1;
    }
  } else {
#pragma unroll
    for (int j = 0; j < 3; ++j) {
      int m = (wave * 3 + j) * 16 + lc;
      float* dst = opart + ((size_t)ks * MPAD + m) * E_DIM + ncl + lg * 4;
      *(float4_t*)dst = acc[j * 2 + 0];
      *(float4_t*)(dst + 16) = acc[j * 2 + 1];
    }
  }
}

// ---------------------------------------------------------------------------
// Attention: grid = 16 heads * 17 q-tiles
// ---------------------------------------------------------------------------
__global__ __launch_bounds__(256) void attn_kernel(
    const unsigned short* __restrict__ qb, const unsigned short* __restrict__ kb,
    const unsigned short* __restrict__ vT, const float* __restrict__ pb,
    unsigned short* __restrict__ ob) {
  int head = blockIdx.x / 17, qt = blockIdx.x % 17;
  int q0 = qt * 16;
  int tid = threadIdx.x, wave = tid >> 6, lane = tid & 63;
  int lg = lane >> 4, lc = lane & 15;
  const unsigned short* qh = qb + (size_t)head * MPAD * 64;
  const unsigned short* kh = kb + (size_t)head * MPAD * 64;
  const unsigned short* vh = vT + (size_t)head * 64 * SPAD;

  short8 aq0 = *(const short8*)(qh + (size_t)(q0 + lc) * 64 + lg * 8);
  short8 aq1 = *(const short8*)(qh + (size_t)(q0 + lc) * 64 + 32 + lg * 8);

  float4_t sc[5];
  int st[5]; int nst = 0;
#pragma unroll
  for (int j = 0; j < 5; ++j) {
    int t = wave + j * 4;
    st[j] = (t < 17) ? t : 0;
    if (t < 17) nst = j + 1;
    sc[j] = (float4_t){0,0,0,0};
  }
#pragma unroll
  for (int j = 0; j < 5; ++j) {
    if (j < nst) {
      const unsigned short* kp = kh + (size_t)(st[j] * 16 + lc) * 64 + lg * 8;
      short8 b0 = *(const short8*)kp;
      short8 b1 = *(const short8*)(kp + 32);
      sc[j] = MFMAs(aq0, b0, sc[j]);
      sc[j] = MFMAs(aq1, b1, sc[j]);
    }
  }
  float mx[4] = {-1e30f, -1e30f, -1e30f, -1e30f};
#pragma unroll
  for (int j = 0; j < 5; ++j) {
    if (j < nst) {
      int sg = st[j] * 16 + lc;
#pragma unroll
      for (int r = 0; r < 4; ++r) {
        float v = sc[j][r] * 0.125f;
        if (sg >= 257) v = -1e30f;
        else if (q0 + lg * 4 + r == 0 && sg >= 1) v += pb[sg - 1];
        sc[j][r] = v;
        mx[r] = fmaxf(mx[r], v);
      }
    }
  }
#pragma unroll
  for (int r = 0; r < 4; ++r) {
    mx[r] = fmaxf(mx[r], __shfl_xor(mx[r], 1, 64));
    mx[r] = fmaxf(mx[r], __shfl_xor(mx[r], 2, 64));
    mx[r] = fmaxf(mx[r], __shfl_xor(mx[r], 4, 64));
    mx[r] = fmaxf(mx[r], __shfl_xor(mx[r], 8, 64));
  }
  __shared__ float smax[4][16];
  __shared__ float sden[4][16];
  __shared__ __align__(16) unsigned short P[16][SPAD];
  if (lc == 0) {
#pragma unroll
    for (int r = 0; r < 4; ++r) smax[wave][lg * 4 + r] = mx[r];
  }
  __syncthreads();
  float fm[4], den[4] = {0, 0, 0, 0};
#pragma unroll
  for (int r = 0; r < 4; ++r) {
    int qq = lg * 4 + r;
    fm[r] = fmaxf(fmaxf(smax[0][qq], smax[1][qq]), fmaxf(smax[2][qq], smax[3][qq]));
  }
#pragma unroll
  for (int j = 0; j < 5; ++j) {
    if (j < nst) {
#pragma unroll
      for (int r = 0; r < 4; ++r) {
        float pe = __expf(sc[j][r] - fm[r]);
        sc[j][r] = pe;
        den[r] += pe;
      }
    }
  }
#pragma unroll
  for (int r = 0; r < 4; ++r) {
    den[r] += __shfl_xor(den[r], 1, 64);
    den[r] += __shfl_xor(den[r], 2, 64);
    den[r] += __shfl_xor(den[r], 4, 64);
    den[r] += __shfl_xor(den[r], 8, 64);
  }
  if (lc == 0) {
#pragma unroll
    for (int r = 0; r < 4; ++r) sden[wave][lg * 4 + r] = den[r];
  }
  P[tid >> 4][272 + (tid & 15)] = 0;
#pragma unroll
  for (int j = 0; j < 5; ++j) {
    if (j < nst) {
#pragma unroll
      for (int r = 0; r < 4; ++r) P[lg * 4 + r][st[j] * 16 + lc] = f2bf(sc[j][r]);
    }
  }
  __syncthreads();
  float denf[4];
#pragma unroll
  for (int r = 0; r < 4; ++r) {
    int qq = lg * 4 + r;
    denf[r] = sden[0][qq] + sden[1][qq] + sden[2][qq] + sden[3][qq];
  }
  int d0 = wave * 16;
  float4_t oa = {0, 0, 0, 0};
#pragma unroll
  for (int s9 = 0; s9 < 9; ++s9) {
    short8 pa = *(const short8*)(&P[lc][s9 * 32 + lg * 8]);
    short8 bv = *(const short8*)(vh + (size_t)(d0 + lc) * SPAD + s9 * 32 + lg * 8);
    oa = MFMAs(pa, bv, oa);
  }
#pragma unroll
  for (int r = 0; r < 4; ++r) {
    int qg = q0 + lg * 4 + r;
    ob[(size_t)qg * E_DIM + head * 64 + d0 + lc] = f2bf(oa[r] / denf[r]);
  }
}

// ---------------------------------------------------------------------------
// reduce_ln
// ---------------------------------------------------------------------------
__global__ __launch_bounds__(256) void reduce_ln_kernel(
    float* __restrict__ x, const float* __restrict__ part, int nparts,
    const float* __restrict__ rbias,
    const float* __restrict__ lns, const float* __restrict__ lnb,
    unsigned short* __restrict__ hout) {
  int m = blockIdx.x, tid = threadIdx.x;
  int c0 = tid * 4;
  float4_t v = *(const float4_t*)(x + (size_t)m * E_DIM + c0);
  if (rbias) v += *(const float4_t*)(rbias + c0);
  for (int s = 0; s < nparts; ++s)
    v += *(const float4_t*)(part + ((size_t)s * MPAD + m) * E_DIM + c0);
  if (nparts > 0) *(float4_t*)(x + (size_t)m * E_DIM + c0) = v;
  float s1 = v[0] + v[1] + v[2] + v[3];
  float s2 = v[0] * v[0] + v[1] * v[1] + v[2] * v[2] + v[3] * v[3];
#pragma unroll
  for (int off = 1; off < 64; off <<= 1) {
    s1 += __shfl_xor(s1, off, 64);
    s2 += __shfl_xor(s2, off, 64);
  }
  __shared__ float red[8];
  int wave = tid >> 6, lane = tid & 63;
  if (lane == 0) { red[wave * 2] = s1; red[wave * 2 + 1] = s2; }
  __syncthreads();
  s1 = red[0] + red[2] + red[4] + red[6];
  s2 = red[1] + red[3] + red[5] + red[7];
  float mean = s1 * (1.f / 1024.f);
  float var = s2 * (1.f / 1024.f) - mean * mean;
  float rstd = rsqrtf(var + 1e-5f);
  float4_t ls = *(const float4_t*)(lns + c0);
  float4_t lb = *(const float4_t*)(lnb + c0);
  ushort4_t hv;
#pragma unroll
  for (int r = 0; r < 4; ++r) hv[r] = f2bf((v[r] - mean) * rstd * ls[r] + lb[r]);
  *(ushort4_t*)(hout + (size_t)m * E_DIM + c0) = hv;
}

// ---------------------------------------------------------------------------
// ROI pool
// ---------------------------------------------------------------------------
__global__ __launch_bounds__(256) void roi_kernel(const float* __restrict__ x,
                                                  const float* __restrict__ Mi,
                                                  float* __restrict__ out) {
  int b = blockIdx.x, tid = threadIdx.x;
  int c0 = tid * 4;
  if (b == 0) {
    *(float4_t*)(out + c0) = *(const float4_t*)(x + c0);
  } else {
    __shared__ float mi[256];
    mi[tid] = Mi[(b - 1) * 256 + tid];
    __syncthreads();
    float4_t acc = {0, 0, 0, 0};
    for (int p = 0; p < 256; ++p) {
      float4_t xv = *(const float4_t*)(x + (size_t)(1 + p) * E_DIM + c0);
      acc += mi[p] * xv;
    }
    *(float4_t*)(out + (size_t)b * E_DIM + c0) = acc;
  }
}

// ---------------------------------------------------------------------------
extern "C" void kernel_launch(void* const* d_in, const int* in_sizes, int n_in,
                              void* d_out, int out_size, void* d_ws, size_t ws_size,
                              hipStream_t stream) {
  const float* frame   = (const float*)d_in[0];
  const float* bboxes  = (const float*)d_in[1];
  const float* conv_w  = (const float*)d_in[2];
  const float* cls_emb = (const float*)d_in[3];
  const float* ln1_s   = (const float*)d_in[4];
  const float* ln1_b   = (const float*)d_in[5];
  const float* wq = (const float*)d_in[6];
  const float* bq = (const float*)d_in[7];
  const float* wk = (const float*)d_in[8];
  const float* bk = (const float*)d_in[9];
  const float* wv = (const float*)d_in[10];
  const float* bv = (const float*)d_in[11];
  const float* wo = (const float*)d_in[12];
  const float* bo = (const float*)d_in[13];
  const float* ln2_s = (const float*)d_in[14];
  const float* ln2_b = (const float*)d_in[15];
  const float* w1 = (const float*)d_in[16];
  const float* b1 = (const float*)d_in[17];
  const float* w2 = (const float*)d_in[18];
  const float* b2 = (const float*)d_in[19];

  char* base = (char*)d_ws;
  auto carve = [&](size_t bytes) {
    char* r = base;
    base += (bytes + 255) & ~(size_t)255;
    return r;
  };
  float* x            = (float*)carve((size_t)257 * E_DIM * 4);
  unsigned short* h   = (unsigned short*)carve((size_t)MPAD * E_DIM * 2);
  unsigned short* qb  = (unsigned short*)carve((size_t)16 * MPAD * 64 * 2);
  unsigned short* kbf = (unsigned short*)carve((size_t)16 * MPAD * 64 * 2);
  unsigned short* vTb = (unsigned short*)carve((size_t)16 * 64 * SPAD * 2);
  unsigned short* ob  = (unsigned short*)carve((size_t)MPAD * E_DIM * 2);
  unsigned short* mb  = (unsigned short*)carve((size_t)MPAD * FF_DIM * 2);
  float* part         = (float*)carve((size_t)4 * MPAD * E_DIM * 4);
  float* pbv          = (float*)carve(256 * 4);
  float* Mi           = (float*)carve(32 * 256 * 4);
  unsigned short* Pm  = (unsigned short*)carve((size_t)256 * KCP * 2);
  unsigned short* Wp  = (unsigned short*)carve((size_t)1024 * KCP * 2);

  prep_kernel<<<1280 + 1020, 256, 0, stream>>>(frame, conv_w, Pm, Wp, h, ob, vTb);
  pb_cls_kernel<<<1, 256, 0, stream>>>(bboxes, cls_emb, pbv, Mi, x);
  conv_gemm<<<64, 256, 0, stream>>>(Pm, Wp, x);
  reduce_ln_kernel<<<257, 256, 0, stream>>>(x, nullptr, 0, nullptr, ln1_s, ln1_b, h);

  for (int l = 0; l < LAYERS; ++l) {
    size_t o2  = (size_t)l * E_DIM * E_DIM;
    size_t o1  = (size_t)l * E_DIM;
    size_t of1 = (size_t)l * E_DIM * FF_DIM;
    size_t ofb = (size_t)l * FF_DIM;
    // QKV: 96 slices (Q 0-31, K 32-63, V 64-95), full M per block, K=1024
    gemm_nk<1024, 0, 8><<<96, 512, 0, stream>>>(h, E_DIM, wq + o2, wk + o2, wv + o2,
                                                bq + o1, bk + o1, bv + o1,
                                                96, qb, kbf, vTb, nullptr, nullptr);
    attn_kernel<<<272, 256, 0, stream>>>(qb, kbf, vTb, pbv, ob);
    // O-proj: 32 slices x KS4 (chunk 256 = 2 tiles) = 128 blocks -> partials
    gemm_nk<1024, 2, 2><<<128, 512, 0, stream>>>(ob, E_DIM, wo + o2, nullptr, nullptr,
                                                 nullptr, nullptr, nullptr,
                                                 32, nullptr, nullptr, nullptr, nullptr, part);
    reduce_ln_kernel<<<257, 256, 0, stream>>>(x, part, 4, bo + o1, ln2_s + o1, ln2_b + o1, h);
    // FF1: 128 slices = 128 blocks, K=1024; fused bias+quickgelu
    gemm_nk<4096, 1, 8><<<128, 512, 0, stream>>>(h, E_DIM, w1 + of1, nullptr, nullptr,
                                                 b1 + ofb, nullptr, nullptr,
                                                 128, nullptr, nullptr, nullptr, mb, nullptr);
    // FF2: 32 slices x KS4 (chunk 1024 = 8 tiles) = 128 blocks -> partials
    gemm_nk<1024, 2, 8><<<128, 512, 0, stream>>>(mb, FF_DIM, w2 + of1, nullptr, nullptr,
                                                 nullptr, nullptr, nullptr,
                                                 32, nullptr, nullptr, nullptr, nullptr, part);
    const float* nls = (l < LAYERS - 1) ? (ln1_s + (size_t)(l + 1) * E_DIM) : ln1_s;
    const float* nlb = (l < LAYERS - 1) ? (ln1_b + (size_t)(l + 1) * E_DIM) : ln1_b;
    reduce_ln_kernel<<<257, 256, 0, stream>>>(x, part, 4, b2 + o1, nls, nlb, h);
  }
  roi_kernel<<<33, 256, 0, stream>>>(x, Mi, (float*)d_out);
}

// Round 11
// 1799.526 us; speedup vs baseline: 1.7480x; 1.7480x over previous
//
#include <hip/hip_runtime.h>
#include <hip/hip_bf16.h>
#include <math.h>

#define E_DIM 1024
#define FF_DIM 4096
#define LAYERS 24
#define MPAD 384      // 24 * 16 token-row padding (rows 257..383 zero / ignored)
#define SPAD 288      // vT / P column padding (9 * 32)
#define KCP 608       // conv K (588) padded to 19*32

typedef __attribute__((ext_vector_type(8))) short short8;
typedef __attribute__((ext_vector_type(8))) __bf16 bf16x8;
typedef __attribute__((ext_vector_type(4))) float float4_t;
typedef __attribute__((ext_vector_type(4))) unsigned short ushort4_t;

union ABu { short8 s; bf16x8 b; };
union BFU { __bf16 b; unsigned short u; };

__device__ __forceinline__ float4_t MFMAs(short8 a, short8 b, float4_t c) {
  ABu ua, ub; ua.s = a; ub.s = b;
  return __builtin_amdgcn_mfma_f32_16x16x32_bf16(ua.b, ub.b, c, 0, 0, 0);
}
__device__ __forceinline__ unsigned short f2bf(float f) {
  BFU x; x.b = (__bf16)f; return x.u;
}

// ---------------------------------------------------------------------------
// prep: im2col frame -> Pm ; conv_w -> Wp ; zero pads of h / ob / vT
// ---------------------------------------------------------------------------
__global__ void prep_kernel(const float* __restrict__ frame, const float* __restrict__ conv_w,
                            unsigned short* __restrict__ Pm, unsigned short* __restrict__ Wp,
                            unsigned short* __restrict__ h, unsigned short* __restrict__ ob,
                            unsigned short* __restrict__ vTb) {
  int b = blockIdx.x, tid = threadIdx.x;
  if (b < 256) {
    int pr = b >> 4, pc = b & 15;
    for (int kk = tid; kk < KCP; kk += 256) {
      unsigned short us = 0;
      if (kk < 588) {
        int c = kk / 196, rem = kk % 196;
        int i = rem / 14, j = rem % 14;
        us = f2bf(frame[c * 224 * 224 + (pr * 14 + i) * 224 + (pc * 14 + j)]);
      }
      Pm[b * KCP + kk] = us;
    }
  } else if (b < 1280) {
    int n = b - 256;
    for (int kk = tid; kk < KCP; kk += 256) {
      unsigned short us = (kk < 588) ? f2bf(conv_w[n * 588 + kk]) : (unsigned short)0;
      Wp[n * KCP + kk] = us;
    }
  } else {
    int idx = (b - 1280) * 256 + tid;
    const int NH = (MPAD - 257) * E_DIM;   // 130048
    const int NO = (MPAD - 272) * E_DIM;   // 114688
    const int NV = 16 * 64 * (SPAD - 272); // 16384
    if (idx < NH) {
      h[257 * E_DIM + idx] = 0;
    } else if (idx < NH + NO) {
      ob[272 * E_DIM + (idx - NH)] = 0;
    } else if (idx < NH + NO + NV) {
      int i = idx - NH - NO;
      vTb[(size_t)(i >> 4) * SPAD + 272 + (i & 15)] = 0;
    }
  }
}

// ---------------------------------------------------------------------------
// pb_cls
// ---------------------------------------------------------------------------
__global__ void pb_cls_kernel(const float* __restrict__ bboxes, const float* __restrict__ cls_emb,
                              float* __restrict__ pb, float* __restrict__ Mi, float* __restrict__ x) {
  __shared__ float sb[128];
  __shared__ float red[256];
  int tid = threadIdx.x;
  if (tid < 128) sb[tid] = bboxes[tid];
  __syncthreads();
  int p = tid;
  float px1 = (float)((p & 15) * 14), py1 = (float)((p >> 4) * 14);
  float px2 = px1 + 14.f, py2 = py1 + 14.f;
  float s = 0.f;
  for (int r = 0; r < 32; ++r) {
    float bx1 = sb[r * 4 + 0], by1 = sb[r * 4 + 1], bx2 = sb[r * 4 + 2], by2 = sb[r * 4 + 3];
    float iw = fmaxf(fminf(bx2, px2) - fmaxf(bx1, px1), 0.f);
    float ih = fmaxf(fminf(by2, py2) - fmaxf(by1, py1), 0.f);
    float ov = iw * ih * (1.f / 196.f);
    Mi[r * 256 + p] = ov;
    s += ov;
  }
  red[tid] = s;
  __syncthreads();
  for (int off = 128; off > 0; off >>= 1) {
    if (tid < off) red[tid] = fmaxf(red[tid], red[tid + off]);
    __syncthreads();
  }
  pb[p] = s / (red[0] + 1e-6f);
  for (int j = 0; j < 4; ++j) x[tid * 4 + j] = cls_emb[tid * 4 + j];
}

// ---------------------------------------------------------------------------
// conv GEMM
// ---------------------------------------------------------------------------
__global__ __launch_bounds__(256) void conv_gemm(const unsigned short* __restrict__ Pm,
                                                 const unsigned short* __restrict__ Wp,
                                                 float* __restrict__ x) {
  int n0 = blockIdx.x * 16;
  int tid = threadIdx.x, wave = tid >> 6, lane = tid & 63;
  int lg = lane >> 4, lc = lane & 15;
  float4_t acc[4] = {{0,0,0,0},{0,0,0,0},{0,0,0,0},{0,0,0,0}};
  const unsigned short* bp = Wp + (size_t)(n0 + lc) * KCP + lg * 8;
  const unsigned short* apt[4];
#pragma unroll
  for (int t = 0; t < 4; ++t) apt[t] = Pm + (size_t)((wave + t * 4) * 16 + lc) * KCP + lg * 8;
  for (int s = 0; s < 19; ++s) {
    short8 bf = *(const short8*)bp; bp += 32;
#pragma unroll
    for (int t = 0; t < 4; ++t) {
      short8 af = *(const short8*)apt[t]; apt[t] += 32;
      acc[t] = MFMAs(af, bf, acc[t]);
    }
  }
#pragma unroll
  for (int t = 0; t < 4; ++t) {
    int mbase = (wave + t * 4) * 16 + lg * 4;
#pragma unroll
    for (int r = 0; r < 4; ++r)
      x[(size_t)(1 + mbase + r) * E_DIM + n0 + lc] = fmaxf(acc[t][r], 0.f);
  }
}

// ---------------------------------------------------------------------------
// GEMM: C[m][n] = A[m][:] (bf16) . W[:][n] (fp32->bf16)
// Block = 256 thr x 32 N-cols x 192 M-rows (M-half) x K-chunk (NK x 128).
// W staged to LDS as bf16 TRANSPOSED [col][k] (8KB/tile, 3 buffers):
//   stage: 16 coalesced dword loads/thread -> f2bf once -> 2x ds_write_b128
//   compute: ONE ds_read_b128 per fragment (8/lane/tile, bank-uniform via
//   16B XOR swizzle key=(col&7)*16 applied identically on write and read).
// T14 pipeline: loads issued 2 iters early; counted vmcnt at segment
// granularity (each iter issues G[16]+A[12]=28): wait 28 / 12 / 0.
// EPI 0: q/k/vT scatter (+bias)  EPI 1: quickgelu (+bias)  EPI 2: fp32 partial
// ---------------------------------------------------------------------------
#define WAITB(n) asm volatile("s_waitcnt vmcnt(" #n ") lgkmcnt(0)\n\ts_barrier" ::: "memory")
#define WAITV(n) asm volatile("s_waitcnt vmcnt(" #n ")" ::: "memory")

template <int NTOT, int EPI, int NK>
__global__ __launch_bounds__(256, 1) void gemm_nk(
    const unsigned short* __restrict__ A, int lda,
    const float* __restrict__ Wa, const float* __restrict__ Wb2, const float* __restrict__ Wc,
    const float* __restrict__ ba, const float* __restrict__ bb, const float* __restrict__ bc,
    int NNT,
    unsigned short* __restrict__ oq, unsigned short* __restrict__ okk,
    unsigned short* __restrict__ ovT, unsigned short* __restrict__ om,
    float* __restrict__ opart) {
  static_assert(NK == 2 || NK >= 3, "NK>=2");
  __shared__ __align__(16) char WbT[3 * 8192];   // 3 bufs x 32 cols x 128 k x bf16
  int b = blockIdx.x;
  int p = ((b >> 4) << 3) | (b & 7);   // pair id: b and b+8 share slice & XCD
  int mh = (b >> 3) & 1;
  int nt = p % NNT, ks = p / NNT;

  int tid = threadIdx.x, wave = tid >> 6, lane = tid & 63;
  int lg = lane >> 4, lc = lane & 15;

  const float* W; const float* bias; int ncl;
  if (EPI == 0) {
    int sel = nt >> 5; ncl = (nt & 31) << 5;
    W = (sel == 0) ? Wa : ((sel == 1) ? Wb2 : Wc);
    bias = (sel == 0) ? ba : ((sel == 1) ? bb : bc);
  } else {
    ncl = nt << 5; W = Wa; bias = ba;
  }

  const int kb0 = ks * (NK * 128);

  // ---- stage mapping: thread -> (col, k-range [rg*16, rg*16+16))
  const int scol = tid & 31, rg = tid >> 5;
  const int skey = (scol & 7) * 16;
  const float* gsrc = W + (size_t)(kb0 + rg * 16) * NTOT + ncl + scol;
  const int wo0 = scol * 256 + ((rg * 32) ^ skey);
  const int wo1 = scol * 256 + ((rg * 32 + 16) ^ skey);

  // ---- A fragment pointers (3 m-tiles per wave)
  const unsigned short* ap[3];
#pragma unroll
  for (int j = 0; j < 3; ++j) {
    int t0 = mh * 12 + wave * 3 + j;
    ap[j] = A + (size_t)(t0 * 16 + lc) * lda + kb0 + lg * 8;
  }

  float4_t acc[6];
#pragma unroll
  for (int i = 0; i < 6; ++i) acc[i] = (float4_t){0, 0, 0, 0};

  float g[2][16];
  short8 av[2][12];
  const int keyr = (lc & 7) * 16;

#define ISSUE_G(slot, t) { _Pragma("unroll") for (int j = 0; j < 16; ++j) \
    g[slot][j] = gsrc[(size_t)(t) * 128 * NTOT + (size_t)j * NTOT]; }
#define ISSUE_A(slot, t) { _Pragma("unroll") for (int s = 0; s < 4; ++s) \
    _Pragma("unroll") for (int j = 0; j < 3; ++j) \
      av[slot][s * 3 + j] = *(const short8*)(ap[j] + (size_t)(t) * 128 + s * 32); }
#define WRITE_G(slot, t) { short8 wlo, whi; \
    _Pragma("unroll") for (int j = 0; j < 8; ++j) { \
      wlo[j] = (short)f2bf(g[slot][j]); whi[j] = (short)f2bf(g[slot][8 + j]); } \
    char* dstb = WbT + ((t) % 3) * 8192; \
    *(short8*)(dstb + wo0) = wlo; \
    *(short8*)(dstb + wo1) = whi; }
#define COMP(t) { const char* ldsb = WbT + ((t) % 3) * 8192; \
    _Pragma("unroll") for (int s = 0; s < 4; ++s) { \
      int o = (s * 64 + lg * 16) ^ keyr; \
      short8 wf0 = *(const short8*)(ldsb + lc * 256 + o); \
      short8 wf1 = *(const short8*)(ldsb + (lc + 16) * 256 + o); \
      _Pragma("unroll") for (int j = 0; j < 3; ++j) { \
        acc[j * 2 + 0] = MFMAs(wf0, av[(t) & 1][s * 3 + j], acc[j * 2 + 0]); \
        acc[j * 2 + 1] = MFMAs(wf1, av[(t) & 1][s * 3 + j], acc[j * 2 + 1]); } } }

  if constexpr (NK == 2) {
    ISSUE_G(0, 0) ISSUE_G(1, 1) ISSUE_A(0, 0) ISSUE_A(1, 1)
    WAITV(24);                       // retire G0,G1; A0,A1 stay in flight
    WRITE_G(0, 0) WRITE_G(1, 1)
    asm volatile("s_waitcnt lgkmcnt(0)\n\ts_barrier" ::: "memory");
    WAITV(12);                       // A0 ready
    COMP(0)
    WAITV(0);                        // A1 ready
    COMP(1)
  } else {
    ISSUE_G(0, 0) ISSUE_G(1, 1) ISSUE_A(0, 0)
    WAITV(28);                       // retire G0; leave G1+A0
    WRITE_G(0, 0)
    ISSUE_G(0, 2) ISSUE_A(1, 1)      // in flight: G1,A0,G2,A1 = 56
#pragma unroll
    for (int t = 0; t < NK; ++t) {
      if (t <= NK - 3)      { WAITB(28); }   // retire G(t+1),A(t)
      else if (t == NK - 2) { WAITB(12); }   // retire G(NK-1),A(NK-2)
      else                  { WAITB(0);  }   // retire A(NK-1)
      if (t + 1 < NK) WRITE_G((t + 1) & 1, t + 1)
      COMP(t)
      if (t + 3 < NK) ISSUE_G((t + 3) & 1, t + 3)
      if (t + 2 < NK) ISSUE_A(t & 1, t + 2)
    }
  }
#undef ISSUE_G
#undef ISSUE_A
#undef WRITE_G
#undef COMP

  float4_t bv0 = {0,0,0,0}, bv1 = {0,0,0,0};
  if (bias) {
    bv0 = *(const float4_t*)(bias + ncl + lg * 4);
    bv1 = *(const float4_t*)(bias + ncl + 16 + lg * 4);
  }

  if (EPI == 0) {
    int sel = nt >> 5;
    int head = ncl >> 6;
    int db0 = (ncl & 63) + lg * 4;
    int db1 = (ncl & 63) + 16 + lg * 4;
#pragma unroll
    for (int j = 0; j < 3; ++j) {
      int tile = mh * 12 + wave * 3 + j;
      int m = tile * 16 + lc;
      if (sel < 2) {
        unsigned short* dst = (sel == 0 ? oq : okk) + ((size_t)(head * MPAD + m)) * 64;
        ushort4_t h0, h1;
#pragma unroll
        for (int r = 0; r < 4; ++r) {
          h0[r] = f2bf(acc[j * 2 + 0][r] + bv0[r]);
          h1[r] = f2bf(acc[j * 2 + 1][r] + bv1[r]);
        }
        *(ushort4_t*)(dst + db0) = h0;
        *(ushort4_t*)(dst + db1) = h1;
      } else if (tile < 17) {   // vT columns only exist for m < 272
#pragma unroll
        for (int r = 0; r < 4; ++r) {
          ovT[(size_t)(head * 64 + db0 + r) * SPAD + m] = f2bf(acc[j * 2 + 0][r] + bv0[r]);
          ovT[(size_t)(head * 64 + db1 + r) * SPAD + m] = f2bf(acc[j * 2 + 1][r] + bv1[r]);
        }
      }
    }
  } else if (EPI == 1) {
#pragma unroll
    for (int j = 0; j < 3; ++j) {
      int m = (mh * 12 + wave * 3 + j) * 16 + lc;
      ushort4_t h0, h1;
#pragma unroll
      for (int r = 0; r < 4; ++r) {
        float v0 = acc[j * 2 + 0][r] + bv0[r];
        float v1 = acc[j * 2 + 1][r] + bv1[r];
        h0[r] = f2bf(v0 / (1.f + __expf(-1.702f * v0)));
        h1[r] = f2bf(v1 / (1.f + __expf(-1.702f * v1)));
      }
      *(ushort4_t*)(om + (size_t)m * FF_DIM + ncl + lg * 4) = h0;
      *(ushort4_t*)(om + (size_t)m * FF_DIM + ncl + 16 + lg * 4) = h1;
    }
  } else {
#pragma unroll
    for (int j = 0; j < 3; ++j) {
      int m = (mh * 12 + wave * 3 + j) * 16 + lc;
      float* dst = opart + ((size_t)ks * MPAD + m) * E_DIM + ncl + lg * 4;
      *(float4_t*)dst = acc[j * 2 + 0];
      *(float4_t*)(dst + 16) = acc[j * 2 + 1];
    }
  }
}

// ---------------------------------------------------------------------------
// Attention: grid = 16 heads * 17 q-tiles
// ---------------------------------------------------------------------------
__global__ __launch_bounds__(256) void attn_kernel(
    const unsigned short* __restrict__ qb, const unsigned short* __restrict__ kb,
    const unsigned short* __restrict__ vT, const float* __restrict__ pb,
    unsigned short* __restrict__ ob) {
  int head = blockIdx.x / 17, qt = blockIdx.x % 17;
  int q0 = qt * 16;
  int tid = threadIdx.x, wave = tid >> 6, lane = tid & 63;
  int lg = lane >> 4, lc = lane & 15;
  const unsigned short* qh = qb + (size_t)head * MPAD * 64;
  const unsigned short* kh = kb + (size_t)head * MPAD * 64;
  const unsigned short* vh = vT + (size_t)head * 64 * SPAD;

  short8 aq0 = *(const short8*)(qh + (size_t)(q0 + lc) * 64 + lg * 8);
  short8 aq1 = *(const short8*)(qh + (size_t)(q0 + lc) * 64 + 32 + lg * 8);

  float4_t sc[5];
  int st[5]; int nst = 0;
#pragma unroll
  for (int j = 0; j < 5; ++j) {
    int t = wave + j * 4;
    st[j] = (t < 17) ? t : 0;
    if (t < 17) nst = j + 1;
    sc[j] = (float4_t){0,0,0,0};
  }
#pragma unroll
  for (int j = 0; j < 5; ++j) {
    if (j < nst) {
      const unsigned short* kp = kh + (size_t)(st[j] * 16 + lc) * 64 + lg * 8;
      short8 b0 = *(const short8*)kp;
      short8 b1 = *(const short8*)(kp + 32);
      sc[j] = MFMAs(aq0, b0, sc[j]);
      sc[j] = MFMAs(aq1, b1, sc[j]);
    }
  }
  float mx[4] = {-1e30f, -1e30f, -1e30f, -1e30f};
#pragma unroll
  for (int j = 0; j < 5; ++j) {
    if (j < nst) {
      int sg = st[j] * 16 + lc;
#pragma unroll
      for (int r = 0; r < 4; ++r) {
        float v = sc[j][r] * 0.125f;
        if (sg >= 257) v = -1e30f;
        else if (q0 + lg * 4 + r == 0 && sg >= 1) v += pb[sg - 1];
        sc[j][r] = v;
        mx[r] = fmaxf(mx[r], v);
      }
    }
  }
#pragma unroll
  for (int r = 0; r < 4; ++r) {
    mx[r] = fmaxf(mx[r], __shfl_xor(mx[r], 1, 64));
    mx[r] = fmaxf(mx[r], __shfl_xor(mx[r], 2, 64));
    mx[r] = fmaxf(mx[r], __shfl_xor(mx[r], 4, 64));
    mx[r] = fmaxf(mx[r], __shfl_xor(mx[r], 8, 64));
  }
  __shared__ float smax[4][16];
  __shared__ float sden[4][16];
  __shared__ __align__(16) unsigned short P[16][SPAD];
  if (lc == 0) {
#pragma unroll
    for (int r = 0; r < 4; ++r) smax[wave][lg * 4 + r] = mx[r];
  }
  __syncthreads();
  float fm[4], den[4] = {0, 0, 0, 0};
#pragma unroll
  for (int r = 0; r < 4; ++r) {
    int qq = lg * 4 + r;
    fm[r] = fmaxf(fmaxf(smax[0][qq], smax[1][qq]), fmaxf(smax[2][qq], smax[3][qq]));
  }
#pragma unroll
  for (int j = 0; j < 5; ++j) {
    if (j < nst) {
#pragma unroll
      for (int r = 0; r < 4; ++r) {
        float pe = __expf(sc[j][r] - fm[r]);
        sc[j][r] = pe;
        den[r] += pe;
      }
    }
  }
#pragma unroll
  for (int r = 0; r < 4; ++r) {
    den[r] += __shfl_xor(den[r], 1, 64);
    den[r] += __shfl_xor(den[r], 2, 64);
    den[r] += __shfl_xor(den[r], 4, 64);
    den[r] += __shfl_xor(den[r], 8, 64);
  }
  if (lc == 0) {
#pragma unroll
    for (int r = 0; r < 4; ++r) sden[wave][lg * 4 + r] = den[r];
  }
  P[tid >> 4][272 + (tid & 15)] = 0;
#pragma unroll
  for (int j = 0; j < 5; ++j) {
    if (j < nst) {
#pragma unroll
      for (int r = 0; r < 4; ++r) P[lg * 4 + r][st[j] * 16 + lc] = f2bf(sc[j][r]);
    }
  }
  __syncthreads();
  float denf[4];
#pragma unroll
  for (int r = 0; r < 4; ++r) {
    int qq = lg * 4 + r;
    denf[r] = sden[0][qq] + sden[1][qq] + sden[2][qq] + sden[3][qq];
  }
  int d0 = wave * 16;
  float4_t oa = {0, 0, 0, 0};
#pragma unroll
  for (int s9 = 0; s9 < 9; ++s9) {
    short8 pa = *(const short8*)(&P[lc][s9 * 32 + lg * 8]);
    short8 bv = *(const short8*)(vh + (size_t)(d0 + lc) * SPAD + s9 * 32 + lg * 8);
    oa = MFMAs(pa, bv, oa);
  }
#pragma unroll
  for (int r = 0; r < 4; ++r) {
    int qg = q0 + lg * 4 + r;
    ob[(size_t)qg * E_DIM + head * 64 + d0 + lc] = f2bf(oa[r] / denf[r]);
  }
}

// ---------------------------------------------------------------------------
// reduce_ln
// ---------------------------------------------------------------------------
__global__ __launch_bounds__(256) void reduce_ln_kernel(
    float* __restrict__ x, const float* __restrict__ part, int nparts,
    const float* __restrict__ rbias,
    const float* __restrict__ lns, const float* __restrict__ lnb,
    unsigned short* __restrict__ hout) {
  int m = blockIdx.x, tid = threadIdx.x;
  int c0 = tid * 4;
  float4_t v = *(const float4_t*)(x + (size_t)m * E_DIM + c0);
  if (rbias) v += *(const float4_t*)(rbias + c0);
  for (int s = 0; s < nparts; ++s)
    v += *(const float4_t*)(part + ((size_t)s * MPAD + m) * E_DIM + c0);
  if (nparts > 0) *(float4_t*)(x + (size_t)m * E_DIM + c0) = v;
  float s1 = v[0] + v[1] + v[2] + v[3];
  float s2 = v[0] * v[0] + v[1] * v[1] + v[2] * v[2] + v[3] * v[3];
#pragma unroll
  for (int off = 1; off < 64; off <<= 1) {
    s1 += __shfl_xor(s1, off, 64);
    s2 += __shfl_xor(s2, off, 64);
  }
  __shared__ float red[8];
  int wave = tid >> 6, lane = tid & 63;
  if (lane == 0) { red[wave * 2] = s1; red[wave * 2 + 1] = s2; }
  __syncthreads();
  s1 = red[0] + red[2] + red[4] + red[6];
  s2 = red[1] + red[3] + red[5] + red[7];
  float mean = s1 * (1.f / 1024.f);
  float var = s2 * (1.f / 1024.f) - mean * mean;
  float rstd = rsqrtf(var + 1e-5f);
  float4_t ls = *(const float4_t*)(lns + c0);
  float4_t lb = *(const float4_t*)(lnb + c0);
  ushort4_t hv;
#pragma unroll
  for (int r = 0; r < 4; ++r) hv[r] = f2bf((v[r] - mean) * rstd * ls[r] + lb[r]);
  *(ushort4_t*)(hout + (size_t)m * E_DIM + c0) = hv;
}

// ---------------------------------------------------------------------------
// ROI pool
// ---------------------------------------------------------------------------
__global__ __launch_bounds__(256) void roi_kernel(const float* __restrict__ x,
                                                  const float* __restrict__ Mi,
                                                  float* __restrict__ out) {
  int b = blockIdx.x, tid = threadIdx.x;
  int c0 = tid * 4;
  if (b == 0) {
    *(float4_t*)(out + c0) = *(const float4_t*)(x + c0);
  } else {
    __shared__ float mi[256];
    mi[tid] = Mi[(b - 1) * 256 + tid];
    __syncthreads();
    float4_t acc = {0, 0, 0, 0};
    for (int p = 0; p < 256; ++p) {
      float4_t xv = *(const float4_t*)(x + (size_t)(1 + p) * E_DIM + c0);
      acc += mi[p] * xv;
    }
    *(float4_t*)(out + (size_t)b * E_DIM + c0) = acc;
  }
}

// ---------------------------------------------------------------------------
extern "C" void kernel_launch(void* const* d_in, const int* in_sizes, int n_in,
                              void* d_out, int out_size, void* d_ws, size_t ws_size,
                              hipStream_t stream) {
  const float* frame   = (const float*)d_in[0];
  const float* bboxes  = (const float*)d_in[1];
  const float* conv_w  = (const float*)d_in[2];
  const float* cls_emb = (const float*)d_in[3];
  const float* ln1_s   = (const float*)d_in[4];
  const float* ln1_b   = (const float*)d_in[5];
  const float* wq = (const float*)d_in[6];
  const float* bq = (const float*)d_in[7];
  const float* wk = (const float*)d_in[8];
  const float* bk = (const float*)d_in[9];
  const float* wv = (const float*)d_in[10];
  const float* bv = (const float*)d_in[11];
  const float* wo = (const float*)d_in[12];
  const float* bo = (const float*)d_in[13];
  const float* ln2_s = (const float*)d_in[14];
  const float* ln2_b = (const float*)d_in[15];
  const float* w1 = (const float*)d_in[16];
  const float* b1 = (const float*)d_in[17];
  const float* w2 = (const float*)d_in[18];
  const float* b2 = (const float*)d_in[19];

  char* base = (char*)d_ws;
  auto carve = [&](size_t bytes) {
    char* r = base;
    base += (bytes + 255) & ~(size_t)255;
    return r;
  };
  float* x            = (float*)carve((size_t)257 * E_DIM * 4);
  unsigned short* h   = (unsigned short*)carve((size_t)MPAD * E_DIM * 2);
  unsigned short* qb  = (unsigned short*)carve((size_t)16 * MPAD * 64 * 2);
  unsigned short* kbf = (unsigned short*)carve((size_t)16 * MPAD * 64 * 2);
  unsigned short* vTb = (unsigned short*)carve((size_t)16 * 64 * SPAD * 2);
  unsigned short* ob  = (unsigned short*)carve((size_t)MPAD * E_DIM * 2);
  unsigned short* mb  = (unsigned short*)carve((size_t)MPAD * FF_DIM * 2);
  float* part         = (float*)carve((size_t)4 * MPAD * E_DIM * 4);
  float* pbv          = (float*)carve(256 * 4);
  float* Mi           = (float*)carve(32 * 256 * 4);
  unsigned short* Pm  = (unsigned short*)carve((size_t)256 * KCP * 2);
  unsigned short* Wp  = (unsigned short*)carve((size_t)1024 * KCP * 2);

  prep_kernel<<<1280 + 1020, 256, 0, stream>>>(frame, conv_w, Pm, Wp, h, ob, vTb);
  pb_cls_kernel<<<1, 256, 0, stream>>>(bboxes, cls_emb, pbv, Mi, x);
  conv_gemm<<<64, 256, 0, stream>>>(Pm, Wp, x);
  reduce_ln_kernel<<<257, 256, 0, stream>>>(x, nullptr, 0, nullptr, ln1_s, ln1_b, h);

  for (int l = 0; l < LAYERS; ++l) {
    size_t o2  = (size_t)l * E_DIM * E_DIM;
    size_t o1  = (size_t)l * E_DIM;
    size_t of1 = (size_t)l * E_DIM * FF_DIM;
    size_t ofb = (size_t)l * FF_DIM;
    // QKV: 96 N-slices x 2 M-halves = 192 blocks, K=1024 (8 tiles)
    gemm_nk<1024, 0, 8><<<192, 256, 0, stream>>>(h, E_DIM, wq + o2, wk + o2, wv + o2,
                                                 bq + o1, bk + o1, bv + o1,
                                                 96, qb, kbf, vTb, nullptr, nullptr);
    attn_kernel<<<272, 256, 0, stream>>>(qb, kbf, vTb, pbv, ob);
    // O-proj: 32 N x 2 Mh x KS4 (chunk 256 = 2 tiles) = 256 blocks -> partials
    gemm_nk<1024, 2, 2><<<256, 256, 0, stream>>>(ob, E_DIM, wo + o2, nullptr, nullptr,
                                                 nullptr, nullptr, nullptr,
                                                 32, nullptr, nullptr, nullptr, nullptr, part);
    reduce_ln_kernel<<<257, 256, 0, stream>>>(x, part, 4, bo + o1, ln2_s + o1, ln2_b + o1, h);
    // FF1: 128 N x 2 Mh = 256 blocks, K=1024 (8 tiles); fused bias+quickgelu
    gemm_nk<4096, 1, 8><<<256, 256, 0, stream>>>(h, E_DIM, w1 + of1, nullptr, nullptr,
                                                 b1 + ofb, nullptr, nullptr,
                                                 128, nullptr, nullptr, nullptr, mb, nullptr);
    // FF2: 32 N x 2 Mh x KS4 (chunk 1024 = 8 tiles) = 256 blocks -> partials
    gemm_nk<1024, 2, 8><<<256, 256, 0, stream>>>(mb, FF_DIM, w2 + of1, nullptr, nullptr,
                                                 nullptr, nullptr, nullptr,
                                                 32, nullptr, nullptr, nullptr, nullptr, part);
    const float* nls = (l < LAYERS - 1) ? (ln1_s + (size_t)(l + 1) * E_DIM) : ln1_s;
    const float* nlb = (l < LAYERS - 1) ? (ln1_b + (size_t)(l + 1) * E_DIM) : ln1_b;
    reduce_ln_kernel<<<257, 256, 0, stream>>>(x, part, 4, b2 + o1, nls, nlb, h);
  }
  roi_kernel<<<33, 256, 0, stream>>>(x, Mi, (float*)d_out);
}

// Round 12
// 1799.358 us; speedup vs baseline: 1.7481x; 1.0001x over previous
//
#include <hip/hip_runtime.h>
#include <hip/hip_bf16.h>
#include <math.h>

#define E_DIM 1024
#define FF_DIM 4096
#define LAYERS 24
#define MPAD 384      // 24 * 16 token-row padding (rows 257..383 zero / ignored)
#define SPAD 288      // vT / P column padding (9 * 32)
#define KCP 608       // conv K (588) padded to 19*32

typedef __attribute__((ext_vector_type(8))) short short8;
typedef __attribute__((ext_vector_type(8))) __bf16 bf16x8;
typedef __attribute__((ext_vector_type(4))) float float4_t;
typedef __attribute__((ext_vector_type(4))) unsigned short ushort4_t;

union ABu { short8 s; bf16x8 b; };
union BFU { __bf16 b; unsigned short u; };

__device__ __forceinline__ float4_t MFMAs(short8 a, short8 b, float4_t c) {
  ABu ua, ub; ua.s = a; ub.s = b;
  return __builtin_amdgcn_mfma_f32_16x16x32_bf16(ua.b, ub.b, c, 0, 0, 0);
}
__device__ __forceinline__ unsigned short f2bf(float f) {
  BFU x; x.b = (__bf16)f; return x.u;
}
__device__ __forceinline__ float bf2f(unsigned short u) {
  BFU x; x.u = u; return (float)x.b;
}

// ---------------------------------------------------------------------------
// prep: im2col frame -> Pm ; conv_w -> Wp ; zero pads of h / ob / vT
// ---------------------------------------------------------------------------
__global__ void prep_kernel(const float* __restrict__ frame, const float* __restrict__ conv_w,
                            unsigned short* __restrict__ Pm, unsigned short* __restrict__ Wp,
                            unsigned short* __restrict__ h, unsigned short* __restrict__ ob,
                            unsigned short* __restrict__ vTb) {
  int b = blockIdx.x, tid = threadIdx.x;
  if (b < 256) {
    int pr = b >> 4, pc = b & 15;
    for (int kk = tid; kk < KCP; kk += 256) {
      unsigned short us = 0;
      if (kk < 588) {
        int c = kk / 196, rem = kk % 196;
        int i = rem / 14, j = rem % 14;
        us = f2bf(frame[c * 224 * 224 + (pr * 14 + i) * 224 + (pc * 14 + j)]);
      }
      Pm[b * KCP + kk] = us;
    }
  } else if (b < 1280) {
    int n = b - 256;
    for (int kk = tid; kk < KCP; kk += 256) {
      unsigned short us = (kk < 588) ? f2bf(conv_w[n * 588 + kk]) : (unsigned short)0;
      Wp[n * KCP + kk] = us;
    }
  } else {
    int idx = (b - 1280) * 256 + tid;
    const int NH = (MPAD - 257) * E_DIM;   // 130048
    const int NO = (MPAD - 272) * E_DIM;   // 114688
    const int NV = 16 * 64 * (SPAD - 272); // 16384
    if (idx < NH) {
      h[257 * E_DIM + idx] = 0;
    } else if (idx < NH + NO) {
      ob[272 * E_DIM + (idx - NH)] = 0;
    } else if (idx < NH + NO + NV) {
      int i = idx - NH - NO;
      vTb[(size_t)(i >> 4) * SPAD + 272 + (i & 15)] = 0;
    }
  }
}

// ---------------------------------------------------------------------------
// pb_cls
// ---------------------------------------------------------------------------
__global__ void pb_cls_kernel(const float* __restrict__ bboxes, const float* __restrict__ cls_emb,
                              float* __restrict__ pb, float* __restrict__ Mi, float* __restrict__ x) {
  __shared__ float sb[128];
  __shared__ float red[256];
  int tid = threadIdx.x;
  if (tid < 128) sb[tid] = bboxes[tid];
  __syncthreads();
  int p = tid;
  float px1 = (float)((p & 15) * 14), py1 = (float)((p >> 4) * 14);
  float px2 = px1 + 14.f, py2 = py1 + 14.f;
  float s = 0.f;
  for (int r = 0; r < 32; ++r) {
    float bx1 = sb[r * 4 + 0], by1 = sb[r * 4 + 1], bx2 = sb[r * 4 + 2], by2 = sb[r * 4 + 3];
    float iw = fmaxf(fminf(bx2, px2) - fmaxf(bx1, px1), 0.f);
    float ih = fmaxf(fminf(by2, py2) - fmaxf(by1, py1), 0.f);
    float ov = iw * ih * (1.f / 196.f);
    Mi[r * 256 + p] = ov;
    s += ov;
  }
  red[tid] = s;
  __syncthreads();
  for (int off = 128; off > 0; off >>= 1) {
    if (tid < off) red[tid] = fmaxf(red[tid], red[tid + off]);
    __syncthreads();
  }
  pb[p] = s / (red[0] + 1e-6f);
  for (int j = 0; j < 4; ++j) x[tid * 4 + j] = cls_emb[tid * 4 + j];
}

// ---------------------------------------------------------------------------
// conv GEMM: 256 blocks = 64 n-tiles x 4 m-quarters; 1 m-tile per wave
// ---------------------------------------------------------------------------
__global__ __launch_bounds__(256) void conv_gemm(const unsigned short* __restrict__ Pm,
                                                 const unsigned short* __restrict__ Wp,
                                                 float* __restrict__ x) {
  int nb = blockIdx.x & 63, mq = blockIdx.x >> 6;
  int n0 = nb * 16;
  int tid = threadIdx.x, wave = tid >> 6, lane = tid & 63;
  int lg = lane >> 4, lc = lane & 15;
  int mt = mq * 4 + wave;          // m-tile 0..15
  float4_t acc = {0, 0, 0, 0};
  const unsigned short* bp = Wp + (size_t)(n0 + lc) * KCP + lg * 8;
  const unsigned short* ap = Pm + (size_t)(mt * 16 + lc) * KCP + lg * 8;
  for (int s = 0; s < 19; ++s) {
    short8 bf = *(const short8*)bp; bp += 32;
    short8 af = *(const short8*)ap; ap += 32;
    acc = MFMAs(af, bf, acc);
  }
  int mbase = mt * 16 + lg * 4;
#pragma unroll
  for (int r = 0; r < 4; ++r)
    x[(size_t)(1 + mbase + r) * E_DIM + n0 + lc] = fmaxf(acc[r], 0.f);
}

// ---------------------------------------------------------------------------
// GEMM: C[m][n] = A[m][:] (bf16) . W[:][n] (fp32->bf16)
// Block = 256 thr x 32 N-cols x 192 M-rows (M-half) x K-chunk (NK x 128).
// W staged to LDS as bf16 TRANSPOSED [col][k], 3 buffers, 16B XOR swizzle.
// T14 pipeline, counted vmcnt (28/12/0). COMP issues its ds_reads BEFORE the
// next tile's ds_writes (LDS ops retire in order -> first MFMA not delayed).
// EPI 0: q/k/vT scatter (+bias)  EPI 1: quickgelu (+bias)  EPI 2: bf16 partial
// ---------------------------------------------------------------------------
#define WAITB(n) asm volatile("s_waitcnt vmcnt(" #n ") lgkmcnt(0)\n\ts_barrier" ::: "memory")
#define WAITV(n) asm volatile("s_waitcnt vmcnt(" #n ")" ::: "memory")

template <int NTOT, int EPI, int NK>
__global__ __launch_bounds__(256, 1) void gemm_nk(
    const unsigned short* __restrict__ A, int lda,
    const float* __restrict__ Wa, const float* __restrict__ Wb2, const float* __restrict__ Wc,
    const float* __restrict__ ba, const float* __restrict__ bb, const float* __restrict__ bc,
    int NNT,
    unsigned short* __restrict__ oq, unsigned short* __restrict__ okk,
    unsigned short* __restrict__ ovT, unsigned short* __restrict__ om,
    unsigned short* __restrict__ opart) {
  static_assert(NK == 2 || NK >= 3, "NK>=2");
  __shared__ __align__(16) char WbT[3 * 8192];   // 3 bufs x 32 cols x 128 k x bf16
  int b = blockIdx.x;
  int p = ((b >> 4) << 3) | (b & 7);   // pair id: b and b+8 share slice & XCD
  int mh = (b >> 3) & 1;
  int nt = p % NNT, ks = p / NNT;

  int tid = threadIdx.x, wave = tid >> 6, lane = tid & 63;
  int lg = lane >> 4, lc = lane & 15;

  const float* W; const float* bias; int ncl;
  if (EPI == 0) {
    int sel = nt >> 5; ncl = (nt & 31) << 5;
    W = (sel == 0) ? Wa : ((sel == 1) ? Wb2 : Wc);
    bias = (sel == 0) ? ba : ((sel == 1) ? bb : bc);
  } else {
    ncl = nt << 5; W = Wa; bias = ba;
  }

  const int kb0 = ks * (NK * 128);

  // ---- stage mapping: thread -> (col, k-range [rg*16, rg*16+16))
  const int scol = tid & 31, rg = tid >> 5;
  const int skey = (scol & 7) * 16;
  const float* gsrc = W + (size_t)(kb0 + rg * 16) * NTOT + ncl + scol;
  const int wo0 = scol * 256 + ((rg * 32) ^ skey);
  const int wo1 = scol * 256 + ((rg * 32 + 16) ^ skey);

  // ---- A fragment pointers (3 m-tiles per wave)
  const unsigned short* ap[3];
#pragma unroll
  for (int j = 0; j < 3; ++j) {
    int t0 = mh * 12 + wave * 3 + j;
    ap[j] = A + (size_t)(t0 * 16 + lc) * lda + kb0 + lg * 8;
  }

  float4_t acc[6];
#pragma unroll
  for (int i = 0; i < 6; ++i) acc[i] = (float4_t){0, 0, 0, 0};

  float g[2][16];
  short8 av[2][12];
  const int keyr = (lc & 7) * 16;

#define ISSUE_G(slot, t) { _Pragma("unroll") for (int j = 0; j < 16; ++j) \
    g[slot][j] = gsrc[(size_t)(t) * 128 * NTOT + (size_t)j * NTOT]; }
#define ISSUE_A(slot, t) { _Pragma("unroll") for (int s = 0; s < 4; ++s) \
    _Pragma("unroll") for (int j = 0; j < 3; ++j) \
      av[slot][s * 3 + j] = *(const short8*)(ap[j] + (size_t)(t) * 128 + s * 32); }
#define WRITE_G(slot, t) { short8 wlo, whi; \
    _Pragma("unroll") for (int j = 0; j < 8; ++j) { \
      wlo[j] = (short)f2bf(g[slot][j]); whi[j] = (short)f2bf(g[slot][8 + j]); } \
    char* dstb = WbT + ((t) % 3) * 8192; \
    *(short8*)(dstb + wo0) = wlo; \
    *(short8*)(dstb + wo1) = whi; }
#define COMP(t) { const char* ldsb = WbT + ((t) % 3) * 8192; \
    _Pragma("unroll") for (int s = 0; s < 4; ++s) { \
      int o = (s * 64 + lg * 16) ^ keyr; \
      short8 wf0 = *(const short8*)(ldsb + lc * 256 + o); \
      short8 wf1 = *(const short8*)(ldsb + (lc + 16) * 256 + o); \
      _Pragma("unroll") for (int j = 0; j < 3; ++j) { \
        acc[j * 2 + 0] = MFMAs(wf0, av[(t) & 1][s * 3 + j], acc[j * 2 + 0]); \
        acc[j * 2 + 1] = MFMAs(wf1, av[(t) & 1][s * 3 + j], acc[j * 2 + 1]); } } }

  if constexpr (NK == 2) {
    ISSUE_G(0, 0) ISSUE_G(1, 1) ISSUE_A(0, 0) ISSUE_A(1, 1)
    WAITV(24);                       // retire G0,G1; A0,A1 stay in flight
    WRITE_G(0, 0) WRITE_G(1, 1)
    asm volatile("s_waitcnt lgkmcnt(0)\n\ts_barrier" ::: "memory");
    WAITV(12);                       // A0 ready
    COMP(0)
    WAITV(0);                        // A1 ready
    COMP(1)
  } else {
    ISSUE_G(0, 0) ISSUE_G(1, 1) ISSUE_A(0, 0)
    WAITV(28);                       // retire G0; leave G1+A0
    WRITE_G(0, 0)
    ISSUE_G(0, 2) ISSUE_A(1, 1)      // in flight: G1,A0,G2,A1 = 56
#pragma unroll
    for (int t = 0; t < NK; ++t) {
      if (t <= NK - 3)      { WAITB(28); }   // retire G(t+1),A(t)
      else if (t == NK - 2) { WAITB(12); }   // retire G(NK-1),A(NK-2)
      else                  { WAITB(0);  }   // retire A(NK-1)
      COMP(t)                                 // ds_reads queue first
      if (t + 1 < NK) WRITE_G((t + 1) & 1, t + 1)
      if (t + 3 < NK) ISSUE_G((t + 3) & 1, t + 3)
      if (t + 2 < NK) ISSUE_A(t & 1, t + 2)
    }
  }
#undef ISSUE_G
#undef ISSUE_A
#undef WRITE_G
#undef COMP

  float4_t bv0 = {0,0,0,0}, bv1 = {0,0,0,0};
  if (bias) {
    bv0 = *(const float4_t*)(bias + ncl + lg * 4);
    bv1 = *(const float4_t*)(bias + ncl + 16 + lg * 4);
  }

  if (EPI == 0) {
    int sel = nt >> 5;
    int head = ncl >> 6;
    int db0 = (ncl & 63) + lg * 4;
    int db1 = (ncl & 63) + 16 + lg * 4;
#pragma unroll
    for (int j = 0; j < 3; ++j) {
      int tile = mh * 12 + wave * 3 + j;
      int m = tile * 16 + lc;
      if (sel < 2) {
        unsigned short* dst = (sel == 0 ? oq : okk) + ((size_t)(head * MPAD + m)) * 64;
        ushort4_t h0, h1;
#pragma unroll
        for (int r = 0; r < 4; ++r) {
          h0[r] = f2bf(acc[j * 2 + 0][r] + bv0[r]);
          h1[r] = f2bf(acc[j * 2 + 1][r] + bv1[r]);
        }
        *(ushort4_t*)(dst + db0) = h0;
        *(ushort4_t*)(dst + db1) = h1;
      } else if (tile < 17) {   // vT columns only exist for m < 272
#pragma unroll
        for (int r = 0; r < 4; ++r) {
          ovT[(size_t)(head * 64 + db0 + r) * SPAD + m] = f2bf(acc[j * 2 + 0][r] + bv0[r]);
          ovT[(size_t)(head * 64 + db1 + r) * SPAD + m] = f2bf(acc[j * 2 + 1][r] + bv1[r]);
        }
      }
    }
  } else if (EPI == 1) {
#pragma unroll
    for (int j = 0; j < 3; ++j) {
      int m = (mh * 12 + wave * 3 + j) * 16 + lc;
      ushort4_t h0, h1;
#pragma unroll
      for (int r = 0; r < 4; ++r) {
        float v0 = acc[j * 2 + 0][r] + bv0[r];
        float v1 = acc[j * 2 + 1][r] + bv1[r];
        h0[r] = f2bf(v0 / (1.f + __expf(-1.702f * v0)));
        h1[r] = f2bf(v1 / (1.f + __expf(-1.702f * v1)));
      }
      *(ushort4_t*)(om + (size_t)m * FF_DIM + ncl + lg * 4) = h0;
      *(ushort4_t*)(om + (size_t)m * FF_DIM + ncl + 16 + lg * 4) = h1;
    }
  } else {
#pragma unroll
    for (int j = 0; j < 3; ++j) {
      int m = (mh * 12 + wave * 3 + j) * 16 + lc;
      unsigned short* dst = opart + ((size_t)ks * MPAD + m) * E_DIM + ncl + lg * 4;
      ushort4_t h0, h1;
#pragma unroll
      for (int r = 0; r < 4; ++r) {
        h0[r] = f2bf(acc[j * 2 + 0][r]);
        h1[r] = f2bf(acc[j * 2 + 1][r]);
      }
      *(ushort4_t*)dst = h0;
      *(ushort4_t*)(dst + 16) = h1;
    }
  }
}

// ---------------------------------------------------------------------------
// Attention: grid = 16 heads * 17 q-tiles
// ---------------------------------------------------------------------------
__global__ __launch_bounds__(256) void attn_kernel(
    const unsigned short* __restrict__ qb, const unsigned short* __restrict__ kb,
    const unsigned short* __restrict__ vT, const float* __restrict__ pb,
    unsigned short* __restrict__ ob) {
  int head = blockIdx.x / 17, qt = blockIdx.x % 17;
  int q0 = qt * 16;
  int tid = threadIdx.x, wave = tid >> 6, lane = tid & 63;
  int lg = lane >> 4, lc = lane & 15;
  const unsigned short* qh = qb + (size_t)head * MPAD * 64;
  const unsigned short* kh = kb + (size_t)head * MPAD * 64;
  const unsigned short* vh = vT + (size_t)head * 64 * SPAD;

  short8 aq0 = *(const short8*)(qh + (size_t)(q0 + lc) * 64 + lg * 8);
  short8 aq1 = *(const short8*)(qh + (size_t)(q0 + lc) * 64 + 32 + lg * 8);

  float4_t sc[5];
  int st[5]; int nst = 0;
#pragma unroll
  for (int j = 0; j < 5; ++j) {
    int t = wave + j * 4;
    st[j] = (t < 17) ? t : 0;
    if (t < 17) nst = j + 1;
    sc[j] = (float4_t){0,0,0,0};
  }
#pragma unroll
  for (int j = 0; j < 5; ++j) {
    if (j < nst) {
      const unsigned short* kp = kh + (size_t)(st[j] * 16 + lc) * 64 + lg * 8;
      short8 b0 = *(const short8*)kp;
      short8 b1 = *(const short8*)(kp + 32);
      sc[j] = MFMAs(aq0, b0, sc[j]);
      sc[j] = MFMAs(aq1, b1, sc[j]);
    }
  }
  float mx[4] = {-1e30f, -1e30f, -1e30f, -1e30f};
#pragma unroll
  for (int j = 0; j < 5; ++j) {
    if (j < nst) {
      int sg = st[j] * 16 + lc;
#pragma unroll
      for (int r = 0; r < 4; ++r) {
        float v = sc[j][r] * 0.125f;
        if (sg >= 257) v = -1e30f;
        else if (q0 + lg * 4 + r == 0 && sg >= 1) v += pb[sg - 1];
        sc[j][r] = v;
        mx[r] = fmaxf(mx[r], v);
      }
    }
  }
#pragma unroll
  for (int r = 0; r < 4; ++r) {
    mx[r] = fmaxf(mx[r], __shfl_xor(mx[r], 1, 64));
    mx[r] = fmaxf(mx[r], __shfl_xor(mx[r], 2, 64));
    mx[r] = fmaxf(mx[r], __shfl_xor(mx[r], 4, 64));
    mx[r] = fmaxf(mx[r], __shfl_xor(mx[r], 8, 64));
  }
  __shared__ float smax[4][16];
  __shared__ float sden[4][16];
  __shared__ __align__(16) unsigned short P[16][SPAD];
  if (lc == 0) {
#pragma unroll
    for (int r = 0; r < 4; ++r) smax[wave][lg * 4 + r] = mx[r];
  }
  __syncthreads();
  float fm[4], den[4] = {0, 0, 0, 0};
#pragma unroll
  for (int r = 0; r < 4; ++r) {
    int qq = lg * 4 + r;
    fm[r] = fmaxf(fmaxf(smax[0][qq], smax[1][qq]), fmaxf(smax[2][qq], smax[3][qq]));
  }
#pragma unroll
  for (int j = 0; j < 5; ++j) {
    if (j < nst) {
#pragma unroll
      for (int r = 0; r < 4; ++r) {
        float pe = __expf(sc[j][r] - fm[r]);
        sc[j][r] = pe;
        den[r] += pe;
      }
    }
  }
#pragma unroll
  for (int r = 0; r < 4; ++r) {
    den[r] += __shfl_xor(den[r], 1, 64);
    den[r] += __shfl_xor(den[r], 2, 64);
    den[r] += __shfl_xor(den[r], 4, 64);
    den[r] += __shfl_xor(den[r], 8, 64);
  }
  if (lc == 0) {
#pragma unroll
    for (int r = 0; r < 4; ++r) sden[wave][lg * 4 + r] = den[r];
  }
  P[tid >> 4][272 + (tid & 15)] = 0;
#pragma unroll
  for (int j = 0; j < 5; ++j) {
    if (j < nst) {
#pragma unroll
      for (int r = 0; r < 4; ++r) P[lg * 4 + r][st[j] * 16 + lc] = f2bf(sc[j][r]);
    }
  }
  __syncthreads();
  float denf[4];
#pragma unroll
  for (int r = 0; r < 4; ++r) {
    int qq = lg * 4 + r;
    denf[r] = sden[0][qq] + sden[1][qq] + sden[2][qq] + sden[3][qq];
  }
  int d0 = wave * 16;
  float4_t oa = {0, 0, 0, 0};
#pragma unroll
  for (int s9 = 0; s9 < 9; ++s9) {
    short8 pa = *(const short8*)(&P[lc][s9 * 32 + lg * 8]);
    short8 bv = *(const short8*)(vh + (size_t)(d0 + lc) * SPAD + s9 * 32 + lg * 8);
    oa = MFMAs(pa, bv, oa);
  }
#pragma unroll
  for (int r = 0; r < 4; ++r) {
    int qg = q0 + lg * 4 + r;
    ob[(size_t)qg * E_DIM + head * 64 + d0 + lc] = f2bf(oa[r] / denf[r]);
  }
}

// ---------------------------------------------------------------------------
// reduce_ln: x[m] += rbias + sum(bf16 partials); LayerNorm(x[m]) -> h
// ---------------------------------------------------------------------------
__global__ __launch_bounds__(256) void reduce_ln_kernel(
    float* __restrict__ x, const unsigned short* __restrict__ part, int nparts,
    const float* __restrict__ rbias,
    const float* __restrict__ lns, const float* __restrict__ lnb,
    unsigned short* __restrict__ hout) {
  int m = blockIdx.x, tid = threadIdx.x;
  int c0 = tid * 4;
  float4_t v = *(const float4_t*)(x + (size_t)m * E_DIM + c0);
  if (rbias) v += *(const float4_t*)(rbias + c0);
  for (int s = 0; s < nparts; ++s) {
    ushort4_t pv = *(const ushort4_t*)(part + ((size_t)s * MPAD + m) * E_DIM + c0);
#pragma unroll
    for (int r = 0; r < 4; ++r) v[r] += bf2f(pv[r]);
  }
  if (nparts > 0) *(float4_t*)(x + (size_t)m * E_DIM + c0) = v;
  float s1 = v[0] + v[1] + v[2] + v[3];
  float s2 = v[0] * v[0] + v[1] * v[1] + v[2] * v[2] + v[3] * v[3];
#pragma unroll
  for (int off = 1; off < 64; off <<= 1) {
    s1 += __shfl_xor(s1, off, 64);
    s2 += __shfl_xor(s2, off, 64);
  }
  __shared__ float red[8];
  int wave = tid >> 6, lane = tid & 63;
  if (lane == 0) { red[wave * 2] = s1; red[wave * 2 + 1] = s2; }
  __syncthreads();
  s1 = red[0] + red[2] + red[4] + red[6];
  s2 = red[1] + red[3] + red[5] + red[7];
  float mean = s1 * (1.f / 1024.f);
  float var = s2 * (1.f / 1024.f) - mean * mean;
  float rstd = rsqrtf(var + 1e-5f);
  float4_t ls = *(const float4_t*)(lns + c0);
  float4_t lb = *(const float4_t*)(lnb + c0);
  ushort4_t hv;
#pragma unroll
  for (int r = 0; r < 4; ++r) hv[r] = f2bf((v[r] - mean) * rstd * ls[r] + lb[r]);
  *(ushort4_t*)(hout + (size_t)m * E_DIM + c0) = hv;
}

// ---------------------------------------------------------------------------
// ROI pool
// ---------------------------------------------------------------------------
__global__ __launch_bounds__(256) void roi_kernel(const float* __restrict__ x,
                                                  const float* __restrict__ Mi,
                                                  float* __restrict__ out) {
  int b = blockIdx.x, tid = threadIdx.x;
  int c0 = tid * 4;
  if (b == 0) {
    *(float4_t*)(out + c0) = *(const float4_t*)(x + c0);
  } else {
    __shared__ float mi[256];
    mi[tid] = Mi[(b - 1) * 256 + tid];
    __syncthreads();
    float4_t acc = {0, 0, 0, 0};
    for (int p = 0; p < 256; ++p) {
      float4_t xv = *(const float4_t*)(x + (size_t)(1 + p) * E_DIM + c0);
      acc += mi[p] * xv;
    }
    *(float4_t*)(out + (size_t)b * E_DIM + c0) = acc;
  }
}

// ---------------------------------------------------------------------------
extern "C" void kernel_launch(void* const* d_in, const int* in_sizes, int n_in,
                              void* d_out, int out_size, void* d_ws, size_t ws_size,
                              hipStream_t stream) {
  const float* frame   = (const float*)d_in[0];
  const float* bboxes  = (const float*)d_in[1];
  const float* conv_w  = (const float*)d_in[2];
  const float* cls_emb = (const float*)d_in[3];
  const float* ln1_s   = (const float*)d_in[4];
  const float* ln1_b   = (const float*)d_in[5];
  const float* wq = (const float*)d_in[6];
  const float* bq = (const float*)d_in[7];
  const float* wk = (const float*)d_in[8];
  const float* bk = (const float*)d_in[9];
  const float* wv = (const float*)d_in[10];
  const float* bv = (const float*)d_in[11];
  const float* wo = (const float*)d_in[12];
  const float* bo = (const float*)d_in[13];
  const float* ln2_s = (const float*)d_in[14];
  const float* ln2_b = (const float*)d_in[15];
  const float* w1 = (const float*)d_in[16];
  const float* b1 = (const float*)d_in[17];
  const float* w2 = (const float*)d_in[18];
  const float* b2 = (const float*)d_in[19];

  char* base = (char*)d_ws;
  auto carve = [&](size_t bytes) {
    char* r = base;
    base += (bytes + 255) & ~(size_t)255;
    return r;
  };
  float* x            = (float*)carve((size_t)257 * E_DIM * 4);
  unsigned short* h   = (unsigned short*)carve((size_t)MPAD * E_DIM * 2);
  unsigned short* qb  = (unsigned short*)carve((size_t)16 * MPAD * 64 * 2);
  unsigned short* kbf = (unsigned short*)carve((size_t)16 * MPAD * 64 * 2);
  unsigned short* vTb = (unsigned short*)carve((size_t)16 * 64 * SPAD * 2);
  unsigned short* ob  = (unsigned short*)carve((size_t)MPAD * E_DIM * 2);
  unsigned short* mb  = (unsigned short*)carve((size_t)MPAD * FF_DIM * 2);
  unsigned short* part= (unsigned short*)carve((size_t)4 * MPAD * E_DIM * 2);
  float* pbv          = (float*)carve(256 * 4);
  float* Mi           = (float*)carve(32 * 256 * 4);
  unsigned short* Pm  = (unsigned short*)carve((size_t)256 * KCP * 2);
  unsigned short* Wp  = (unsigned short*)carve((size_t)1024 * KCP * 2);

  prep_kernel<<<1280 + 1020, 256, 0, stream>>>(frame, conv_w, Pm, Wp, h, ob, vTb);
  pb_cls_kernel<<<1, 256, 0, stream>>>(bboxes, cls_emb, pbv, Mi, x);
  conv_gemm<<<256, 256, 0, stream>>>(Pm, Wp, x);
  reduce_ln_kernel<<<257, 256, 0, stream>>>(x, nullptr, 0, nullptr, ln1_s, ln1_b, h);

  for (int l = 0; l < LAYERS; ++l) {
    size_t o2  = (size_t)l * E_DIM * E_DIM;
    size_t o1  = (size_t)l * E_DIM;
    size_t of1 = (size_t)l * E_DIM * FF_DIM;
    size_t ofb = (size_t)l * FF_DIM;
    // QKV: 96 N-slices x 2 M-halves = 192 blocks, K=1024 (8 tiles)
    gemm_nk<1024, 0, 8><<<192, 256, 0, stream>>>(h, E_DIM, wq + o2, wk + o2, wv + o2,
                                                 bq + o1, bk + o1, bv + o1,
                                                 96, qb, kbf, vTb, nullptr, nullptr);
    attn_kernel<<<272, 256, 0, stream>>>(qb, kbf, vTb, pbv, ob);
    // O-proj: 32 N x 2 Mh x KS4 (chunk 256 = 2 tiles) = 256 blocks -> bf16 partials
    gemm_nk<1024, 2, 2><<<256, 256, 0, stream>>>(ob, E_DIM, wo + o2, nullptr, nullptr,
                                                 nullptr, nullptr, nullptr,
                                                 32, nullptr, nullptr, nullptr, nullptr, part);
    reduce_ln_kernel<<<257, 256, 0, stream>>>(x, part, 4, bo + o1, ln2_s + o1, ln2_b + o1, h);
    // FF1: 128 N x 2 Mh = 256 blocks, K=1024 (8 tiles); fused bias+quickgelu
    gemm_nk<4096, 1, 8><<<256, 256, 0, stream>>>(h, E_DIM, w1 + of1, nullptr, nullptr,
                                                 b1 + ofb, nullptr, nullptr,
                                                 128, nullptr, nullptr, nullptr, mb, nullptr);
    // FF2: 32 N x 2 Mh x KS4 (chunk 1024 = 8 tiles) = 256 blocks -> bf16 partials
    gemm_nk<1024, 2, 8><<<256, 256, 0, stream>>>(mb, FF_DIM, w2 + of1, nullptr, nullptr,
                                                 nullptr, nullptr, nullptr,
                                                 32, nullptr, nullptr, nullptr, nullptr, part);
    const float* nls = (l < LAYERS - 1) ? (ln1_s + (size_t)(l + 1) * E_DIM) : ln1_s;
    const float* nlb = (l < LAYERS - 1) ? (ln1_b + (size_t)(l + 1) * E_DIM) : ln1_b;
    reduce_ln_kernel<<<257, 256, 0, stream>>>(x, part, 4, b2 + o1, nls, nlb, h);
  }
  roi_kernel<<<33, 256, 0, stream>>>(x, Mi, (float*)d_out);
}